// Round 1
// baseline (331.864 us; speedup 1.0000x reference)
//
#include <hip/hip_runtime.h>
#include <stdint.h>

// Quantized linear (distiller RangeLinearQuantParamLayerWrapper):
//   maxabs(x), maxabs(W) -> int8 quantize -> exact i8 GEMM (int32 accum)
//   -> maxabs(accum) -> requantize -> dequantize f32.
//
// x: [8192, 4096] f32, W: [4096, 4096] f32 (out,in). out: [8192,4096] f32.

using i32x4 = __attribute__((ext_vector_type(4))) int;

#define M_DIM 8192
#define N_DIM 4096
#define K_DIM 4096

#define BM 128
#define BN 128
#define BK 128

// ---------------- scalar init ----------------
__global__ void k_init(unsigned* sc) {
    sc[0] = 0u;  // maxabs(x) bits
    sc[1] = 0u;  // maxabs(W) bits
    sc[2] = 0u;  // max|accum| (int as unsigned)
}

// ---------------- absmax over f32 (bits trick: abs f32 compares as uint) ----------------
__global__ __launch_bounds__(256) void k_absmax(const float4* __restrict__ src, int n4,
                                                unsigned* __restrict__ out) {
    unsigned m = 0;
    int stride = gridDim.x * blockDim.x;
    for (int i = blockIdx.x * blockDim.x + threadIdx.x; i < n4; i += stride) {
        float4 v = src[i];
        unsigned a = __float_as_uint(v.x) & 0x7fffffffu;
        unsigned b = __float_as_uint(v.y) & 0x7fffffffu;
        unsigned c = __float_as_uint(v.z) & 0x7fffffffu;
        unsigned d = __float_as_uint(v.w) & 0x7fffffffu;
        m = max(m, max(max(a, b), max(c, d)));
    }
    for (int off = 32; off; off >>= 1)
        m = max(m, (unsigned)__shfl_xor((int)m, off));
    __shared__ unsigned wm[4];
    int ln = threadIdx.x & 63, wv = threadIdx.x >> 6;
    if (ln == 0) wm[wv] = m;
    __syncthreads();
    if (threadIdx.x == 0)
        atomicMax(out, max(max(wm[0], wm[1]), max(wm[2], wm[3])));
}

// ---------------- symmetric int8 quantize, 4 elements -> packed u32 ----------------
__global__ __launch_bounds__(256) void k_quant(const float4* __restrict__ src,
                                               unsigned* __restrict__ dst, int n4,
                                               const unsigned* __restrict__ maxbits) {
    float scale = 127.0f / __uint_as_float(*maxbits);
    int stride = gridDim.x * blockDim.x;
    for (int i = blockIdx.x * blockDim.x + threadIdx.x; i < n4; i += stride) {
        float4 v = src[i];
        int q0 = min(127, max(-128, (int)rintf(v.x * scale)));
        int q1 = min(127, max(-128, (int)rintf(v.y * scale)));
        int q2 = min(127, max(-128, (int)rintf(v.z * scale)));
        int q3 = min(127, max(-128, (int)rintf(v.w * scale)));
        dst[i] = (unsigned)(q0 & 0xff) | ((unsigned)(q1 & 0xff) << 8) |
                 ((unsigned)(q2 & 0xff) << 16) | ((unsigned)(q3 & 0xff) << 24);
    }
}

// ---------------- i8 GEMM: C[m][n] = sum_k A[m][k]*B[n][k], int32 exact ----------------
// 128x128 tile, BK=128, 4 waves (2x2), each wave 64x64 via 4x4 frags of 16x16x64.
// LDS: linear dest for global_load_lds; XOR chunk swizzle applied on the
// per-lane GLOBAL source address and again on the ds_read address (involution),
// so ds_read_b128 spreads uniformly over all 32 banks.
__global__ __launch_bounds__(256) void k_gemm(const char* __restrict__ Aq,
                                              const char* __restrict__ Bq,
                                              int* __restrict__ C,
                                              unsigned* __restrict__ maxAcc) {
    __shared__ char lA[BM * BK];  // 16 KiB
    __shared__ char lB[BN * BK];  // 16 KiB

    const int bx = blockIdx.x;   // N tile
    const int by = blockIdx.y;   // M tile
    const int t  = threadIdx.x;
    const int ln = t & 63;
    const int wv = t >> 6;
    const int wr  = wv >> 1;     // wave row (0..1)
    const int wcl = wv & 1;      // wave col (0..1)
    const int lr = ln & 15;      // lane row within 16x16 frag
    const int lk = ln >> 4;      // lane k-group (0..3)

    i32x4 acc[4][4];
#pragma unroll
    for (int i = 0; i < 4; ++i)
#pragma unroll
        for (int j = 0; j < 4; ++j) acc[i][j] = (i32x4)(0);

    const size_t arow0 = (size_t)by * BM;
    const size_t brow0 = (size_t)bx * BN;

    for (int ks = 0; ks < K_DIM / BK; ++ks) {
        const int k0 = ks * BK;
        // stage A and B tiles: 1024 chunks of 16B each; 256 threads x 4 iters
#pragma unroll
        for (int it = 0; it < 4; ++it) {
            const int chunkBase = it * 256 + (wv << 6);  // wave-uniform
            const int chunk = chunkBase + ln;
            const int row = chunk >> 3;           // 0..127
            const int gc = (chunk & 7) ^ (row & 7);  // inverse (=same) swizzle
            const char* ga = Aq + ((arow0 + row) << 12) + k0 + (gc << 4);
            __builtin_amdgcn_global_load_lds(
                (const __attribute__((address_space(1))) void*)ga,
                (__attribute__((address_space(3))) void*)(lA + chunkBase * 16), 16, 0, 0);
            const char* gb = Bq + ((brow0 + row) << 12) + k0 + (gc << 4);
            __builtin_amdgcn_global_load_lds(
                (const __attribute__((address_space(1))) void*)gb,
                (__attribute__((address_space(3))) void*)(lB + chunkBase * 16), 16, 0, 0);
        }
        __syncthreads();

#pragma unroll
        for (int h = 0; h < 2; ++h) {
            i32x4 af[4], bf[4];
#pragma unroll
            for (int mi = 0; mi < 4; ++mi) {
                const int row = (wr << 6) + (mi << 4) + lr;
                const int sc = ((h << 2) + lk) ^ (row & 7);
                af[mi] = *(const i32x4*)(lA + row * BK + (sc << 4));
            }
#pragma unroll
            for (int ni = 0; ni < 4; ++ni) {
                const int row = (wcl << 6) + (ni << 4) + lr;
                const int sc = ((h << 2) + lk) ^ (row & 7);
                bf[ni] = *(const i32x4*)(lB + row * BK + (sc << 4));
            }
#pragma unroll
            for (int mi = 0; mi < 4; ++mi)
#pragma unroll
                for (int ni = 0; ni < 4; ++ni)
                    acc[mi][ni] = __builtin_amdgcn_mfma_i32_16x16x64_i8(
                        af[mi], bf[ni], acc[mi][ni], 0, 0, 0);
        }
        __syncthreads();
    }

    // epilogue: C/D layout col = lane&15, row = (lane>>4)*4 + reg
    int amax = 0;
#pragma unroll
    for (int mi = 0; mi < 4; ++mi) {
#pragma unroll
        for (int ni = 0; ni < 4; ++ni) {
            const int row0 = (int)arow0 + (wr << 6) + (mi << 4) + (lk << 2);
            const int col  = (int)brow0 + (wcl << 6) + (ni << 4) + lr;
            i32x4 v = acc[mi][ni];
#pragma unroll
            for (int j = 0; j < 4; ++j) {
                C[(size_t)(row0 + j) * N_DIM + col] = v[j];
                int a = v[j] < 0 ? -v[j] : v[j];
                amax = max(amax, a);
            }
        }
    }
    for (int off = 32; off; off >>= 1)
        amax = max(amax, __shfl_xor(amax, off));
    __shared__ int wmax[4];
    if (ln == 0) wmax[wv] = amax;
    __syncthreads();
    if (t == 0)
        atomicMax(maxAcc, (unsigned)max(max(wmax[0], wmax[1]), max(wmax[2], wmax[3])));
}

// ---------------- requantize int32 accum -> f32 output, in place ----------------
__global__ __launch_bounds__(256) void k_requant(int4* __restrict__ buf, int n4,
                                                 const unsigned* __restrict__ sc) {
    const float maxX = __uint_as_float(sc[0]);
    const float maxW = __uint_as_float(sc[1]);
    const float maxA = (float)(int)sc[2];           // < 2^24, exact
    const float in_scale = 127.0f / maxX;
    const float w_scale  = 127.0f / maxW;
    const float accum_scale = in_scale * w_scale;
    const float requant = 127.0f / maxA;            // out_scale / accum_scale
    const float out_scale = requant * accum_scale;  // 127 * accum_scale / maxA
    int stride = gridDim.x * blockDim.x;
    for (int i = blockIdx.x * blockDim.x + threadIdx.x; i < n4; i += stride) {
        int4 v = buf[i];
        float4 o;
        o.x = fminf(127.f, fmaxf(-128.f, rintf((float)v.x * requant))) / out_scale;
        o.y = fminf(127.f, fmaxf(-128.f, rintf((float)v.y * requant))) / out_scale;
        o.z = fminf(127.f, fmaxf(-128.f, rintf((float)v.z * requant))) / out_scale;
        o.w = fminf(127.f, fmaxf(-128.f, rintf((float)v.w * requant))) / out_scale;
        ((float4*)buf)[i] = o;
    }
}

extern "C" void kernel_launch(void* const* d_in, const int* in_sizes, int n_in,
                              void* d_out, int out_size, void* d_ws, size_t ws_size,
                              hipStream_t stream) {
    const float* x = (const float*)d_in[0];  // [8192, 4096]
    const float* W = (const float*)d_in[1];  // [4096, 4096]

    // workspace layout: [0..255] scalars, then x_q (32MB), then W_q (16MB)
    unsigned* sc = (unsigned*)d_ws;
    char* xq = (char*)d_ws + 256;
    char* wq = xq + (size_t)M_DIM * K_DIM;

    k_init<<<1, 1, 0, stream>>>(sc);
    k_absmax<<<2048, 256, 0, stream>>>((const float4*)x, M_DIM * K_DIM / 4, sc + 0);
    k_absmax<<<1024, 256, 0, stream>>>((const float4*)W, N_DIM * K_DIM / 4, sc + 1);
    k_quant<<<2048, 256, 0, stream>>>((const float4*)x, (unsigned*)xq, M_DIM * K_DIM / 4, sc + 0);
    k_quant<<<1024, 256, 0, stream>>>((const float4*)W, (unsigned*)wq, N_DIM * K_DIM / 4, sc + 1);

    dim3 g(N_DIM / BN, M_DIM / BM);
    k_gemm<<<g, 256, 0, stream>>>(xq, wq, (int*)d_out, sc + 2);

    k_requant<<<2048, 256, 0, stream>>>((int4*)d_out, M_DIM * N_DIM / 4, sc);
}

// Round 2
// 308.552 us; speedup vs baseline: 1.0756x; 1.0756x over previous
//
#include <hip/hip_runtime.h>
#include <stdint.h>

// Quantized linear (distiller RangeLinearQuantParamLayerWrapper):
//   maxabs(x), maxabs(W) -> int8 quantize -> exact i8 GEMM (int32 accum)
//   -> maxabs(accum) -> requantize -> dequantize f32.
//
// GEMM: 256x256 tile, BK=128 i8, 8 waves, 8-phase schedule with counted
// vmcnt (T2+T3+T4+T5 port of the bf16 8-phase template, byte-identical
// layout since 128 i8 = 128 B = 64 bf16 rows).

using i32x4 = __attribute__((ext_vector_type(4))) int;

#define M_DIM 8192
#define N_DIM 4096
#define K_DIM 4096

#define BM 256
#define BN 256
#define BKB 128              // K-tile in bytes (= i8 elements)
#define NKT (K_DIM / BKB)    // 32

// ---------------- scalar init ----------------
__global__ void k_init(unsigned* sc) {
    sc[0] = 0u;  // maxabs(x) bits
    sc[1] = 0u;  // maxabs(W) bits
    sc[2] = 0u;  // max|accum|
}

// ---------------- absmax over f32 ----------------
__global__ __launch_bounds__(256) void k_absmax(const float4* __restrict__ src, int n4,
                                                unsigned* __restrict__ out) {
    unsigned m = 0;
    int stride = gridDim.x * blockDim.x;
    for (int i = blockIdx.x * blockDim.x + threadIdx.x; i < n4; i += stride) {
        float4 v = src[i];
        unsigned a = __float_as_uint(v.x) & 0x7fffffffu;
        unsigned b = __float_as_uint(v.y) & 0x7fffffffu;
        unsigned c = __float_as_uint(v.z) & 0x7fffffffu;
        unsigned d = __float_as_uint(v.w) & 0x7fffffffu;
        m = max(m, max(max(a, b), max(c, d)));
    }
    for (int off = 32; off; off >>= 1)
        m = max(m, (unsigned)__shfl_xor((int)m, off));
    __shared__ unsigned wm[4];
    int ln = threadIdx.x & 63, wv = threadIdx.x >> 6;
    if (ln == 0) wm[wv] = m;
    __syncthreads();
    if (threadIdx.x == 0)
        atomicMax(out, max(max(wm[0], wm[1]), max(wm[2], wm[3])));
}

// ---------------- symmetric int8 quantize ----------------
__global__ __launch_bounds__(256) void k_quant(const float4* __restrict__ src,
                                               unsigned* __restrict__ dst, int n4,
                                               const unsigned* __restrict__ maxbits) {
    float scale = 127.0f / __uint_as_float(*maxbits);
    int stride = gridDim.x * blockDim.x;
    for (int i = blockIdx.x * blockDim.x + threadIdx.x; i < n4; i += stride) {
        float4 v = src[i];
        int q0 = min(127, max(-128, (int)rintf(v.x * scale)));
        int q1 = min(127, max(-128, (int)rintf(v.y * scale)));
        int q2 = min(127, max(-128, (int)rintf(v.z * scale)));
        int q3 = min(127, max(-128, (int)rintf(v.w * scale)));
        dst[i] = (unsigned)(q0 & 0xff) | ((unsigned)(q1 & 0xff) << 8) |
                 ((unsigned)(q2 & 0xff) << 16) | ((unsigned)(q3 & 0xff) << 24);
    }
}

// ---------------- i8 GEMM, 256^2 8-phase ----------------
// LDS: lA[2][256][128], lB[2][256][128] = 128 KiB. XOR chunk swizzle
// (slot cs holds global chunk cs^(row&7)); linear gload_lds dest +
// inverse-swizzled global source + swizzled ds_read (both-sides rule).
//
// Per K-tile kt (slot s=kt&1), phases:
//  P0: read a03(8)+b01(4); MFMA a03*b01
//  P1: read b23(4);        MFMA a03*b23   (a03 dies)
//  P2: read a47(8); STAGE B(kt+2)->s; MFMA a47*b01 (b01 dies)
//  P3: STAGE A(kt+2)->s; vmcnt(8); MFMA a47*b23
// Safety: A-half reads done by P2's lgkm -> A restage at P3; B-half reads
// done by P1's lgkm -> B restage at P2 (different region from P2's A reads).
// vmcnt(8) leaves kt+2's 8 loads (4 half-tiles) in flight, forces kt+1 landed.
__global__ __launch_bounds__(512, 2) void k_gemm(const char* __restrict__ Aq,
                                                 const char* __restrict__ Bq,
                                                 int* __restrict__ C,
                                                 unsigned* __restrict__ maxAcc) {
    __shared__ __align__(16) char lds[131072];
    __shared__ int wmax[8];
    char* lA = lds;            // [2][256][128]
    char* lB = lds + 65536;    // [2][256][128]

    const int t = threadIdx.x;
    const int ln = t & 63;
    const int wv = t >> 6;
    const int wr = wv >> 2;    // wave M half (0..1) -> rows wr*128..+127
    const int wc = wv & 3;     // wave N quarter (0..3) -> cols wc*64..+63
    const int lr = ln & 15;
    const int lk = ln >> 4;

    // XCD-aware swizzle: 512 wgs, 512%8==0 -> simple bijective form
    const int bid = blockIdx.x;
    const int swz = (bid & 7) * 64 + (bid >> 3);
    const int bx = swz & 15;   // N tile (16)
    const int by = swz >> 4;   // M tile (32)
    const size_t arow0 = (size_t)by * BM;
    const size_t brow0 = (size_t)bx * BN;

    i32x4 acc[8][4];
#pragma unroll
    for (int i = 0; i < 8; ++i)
#pragma unroll
        for (int j = 0; j < 4; ++j) acc[i][j] = (i32x4)(0);

    auto STAGE = [&](int kt, int j) {  // j: 0,1 = A halves; 2,3 = B halves
        const int slot = kt & 1;
        const char* gbase = (j < 2) ? Aq : Bq;
        char* lbase = ((j < 2) ? lA : lB) + slot * 32768 + (j & 1) * 16384;
        const size_t grow0 = ((j < 2) ? arow0 : brow0) + (size_t)((j & 1) << 7);
        const int k0 = kt * BKB;
#pragma unroll
        for (int it = 0; it < 2; ++it) {
            const int chunkBase = it * 512 + (wv << 6);  // wave-uniform
            const int chunk = chunkBase + ln;
            const int row = chunk >> 3;                  // 0..127 within half
            const int gc = (chunk & 7) ^ (row & 7);      // inverse swizzle on src
            const char* g = gbase + ((grow0 + (size_t)row) << 12) + k0 + (gc << 4);
            __builtin_amdgcn_global_load_lds(
                (const __attribute__((address_space(1))) void*)g,
                (__attribute__((address_space(3))) void*)(lbase + chunkBase * 16), 16, 0, 0);
        }
    };

    // ---- prologue: stage kt0 + kt1 (16 loads), wait kt0 landed ----
#pragma unroll
    for (int h = 0; h < 8; ++h) STAGE(h >> 2, h & 3);
    asm volatile("s_waitcnt vmcnt(8)" ::: "memory");
    __builtin_amdgcn_s_barrier();
    __builtin_amdgcn_sched_barrier(0);

    for (int kt = 0; kt < NKT; ++kt) {
        const int slot = kt & 1;
        const char* sA = lA + slot * 32768;
        const char* sB = lB + slot * 32768;
        i32x4 a0[4][2], a4[4][2], b0[2][2], b2[2][2];

        // ================ P0: read a03 + b01; MFMA a03 x b01 ================
#pragma unroll
        for (int mi = 0; mi < 4; ++mi)
#pragma unroll
            for (int kh = 0; kh < 2; ++kh) {
                const int r = (wr << 7) + (mi << 4) + lr;
                const int cs = ((kh << 2) | lk) ^ (r & 7);
                a0[mi][kh] = *(const i32x4*)(sA + r * 128 + (cs << 4));
            }
#pragma unroll
        for (int ni = 0; ni < 2; ++ni)
#pragma unroll
            for (int kh = 0; kh < 2; ++kh) {
                const int r = (wc << 6) + (ni << 4) + lr;
                const int cs = ((kh << 2) | lk) ^ (r & 7);
                b0[ni][kh] = *(const i32x4*)(sB + r * 128 + (cs << 4));
            }
        __builtin_amdgcn_s_barrier();
        __builtin_amdgcn_sched_barrier(0);
        asm volatile("s_waitcnt lgkmcnt(0)" ::: "memory");
        __builtin_amdgcn_sched_barrier(0);
        __builtin_amdgcn_s_setprio(1);
#pragma unroll
        for (int mi = 0; mi < 4; ++mi)
#pragma unroll
            for (int ni = 0; ni < 2; ++ni)
#pragma unroll
                for (int kh = 0; kh < 2; ++kh)
                    acc[mi][ni] = __builtin_amdgcn_mfma_i32_16x16x64_i8(
                        a0[mi][kh], b0[ni][kh], acc[mi][ni], 0, 0, 0);
        __builtin_amdgcn_s_setprio(0);
        __builtin_amdgcn_s_barrier();
        __builtin_amdgcn_sched_barrier(0);

        // ================ P1: read b23; MFMA a03 x b23 ================
#pragma unroll
        for (int ni = 0; ni < 2; ++ni)
#pragma unroll
            for (int kh = 0; kh < 2; ++kh) {
                const int r = (wc << 6) + ((ni + 2) << 4) + lr;
                const int cs = ((kh << 2) | lk) ^ (r & 7);
                b2[ni][kh] = *(const i32x4*)(sB + r * 128 + (cs << 4));
            }
        __builtin_amdgcn_s_barrier();
        __builtin_amdgcn_sched_barrier(0);
        asm volatile("s_waitcnt lgkmcnt(0)" ::: "memory");
        __builtin_amdgcn_sched_barrier(0);
        __builtin_amdgcn_s_setprio(1);
#pragma unroll
        for (int mi = 0; mi < 4; ++mi)
#pragma unroll
            for (int ni = 0; ni < 2; ++ni)
#pragma unroll
                for (int kh = 0; kh < 2; ++kh)
                    acc[mi][ni + 2] = __builtin_amdgcn_mfma_i32_16x16x64_i8(
                        a0[mi][kh], b2[ni][kh], acc[mi][ni + 2], 0, 0, 0);
        __builtin_amdgcn_s_setprio(0);
        __builtin_amdgcn_s_barrier();
        __builtin_amdgcn_sched_barrier(0);

        // ============ P2: read a47; stage B(kt+2); MFMA a47 x b01 ============
#pragma unroll
        for (int mi = 0; mi < 4; ++mi)
#pragma unroll
            for (int kh = 0; kh < 2; ++kh) {
                const int r = (wr << 7) + ((mi + 4) << 4) + lr;
                const int cs = ((kh << 2) | lk) ^ (r & 7);
                a4[mi][kh] = *(const i32x4*)(sA + r * 128 + (cs << 4));
            }
        if (kt + 2 < NKT) { STAGE(kt + 2, 2); STAGE(kt + 2, 3); }
        __builtin_amdgcn_s_barrier();
        __builtin_amdgcn_sched_barrier(0);
        asm volatile("s_waitcnt lgkmcnt(0)" ::: "memory");
        __builtin_amdgcn_sched_barrier(0);
        __builtin_amdgcn_s_setprio(1);
#pragma unroll
        for (int mi = 0; mi < 4; ++mi)
#pragma unroll
            for (int ni = 0; ni < 2; ++ni)
#pragma unroll
                for (int kh = 0; kh < 2; ++kh)
                    acc[mi + 4][ni] = __builtin_amdgcn_mfma_i32_16x16x64_i8(
                        a4[mi][kh], b0[ni][kh], acc[mi + 4][ni], 0, 0, 0);
        __builtin_amdgcn_s_setprio(0);
        __builtin_amdgcn_s_barrier();
        __builtin_amdgcn_sched_barrier(0);

        // ============ P3: stage A(kt+2); vmcnt(8); MFMA a47 x b23 ============
        if (kt + 2 < NKT) { STAGE(kt + 2, 0); STAGE(kt + 2, 1); }
        asm volatile("s_waitcnt vmcnt(8)" ::: "memory");
        __builtin_amdgcn_s_barrier();
        __builtin_amdgcn_sched_barrier(0);
        __builtin_amdgcn_s_setprio(1);
#pragma unroll
        for (int mi = 0; mi < 4; ++mi)
#pragma unroll
            for (int ni = 0; ni < 2; ++ni)
#pragma unroll
                for (int kh = 0; kh < 2; ++kh)
                    acc[mi + 4][ni + 2] = __builtin_amdgcn_mfma_i32_16x16x64_i8(
                        a4[mi][kh], b2[ni][kh], acc[mi + 4][ni + 2], 0, 0, 0);
        __builtin_amdgcn_s_setprio(0);
        __builtin_amdgcn_s_barrier();
        __builtin_amdgcn_sched_barrier(0);
    }

    // ---- epilogue: C write + |acc| max. C/D: col=lane&15, row=(lane>>4)*4+reg
    int amax = 0;
#pragma unroll
    for (int mi = 0; mi < 8; ++mi) {
#pragma unroll
        for (int ni = 0; ni < 4; ++ni) {
            const int row0 = (int)arow0 + (wr << 7) + (mi << 4) + (lk << 2);
            const int col  = (int)brow0 + (wc << 6) + (ni << 4) + lr;
            i32x4 v = acc[mi][ni];
#pragma unroll
            for (int j = 0; j < 4; ++j) {
                C[(size_t)(row0 + j) * N_DIM + col] = v[j];
                int a = v[j] < 0 ? -v[j] : v[j];
                amax = max(amax, a);
            }
        }
    }
    for (int off = 32; off; off >>= 1)
        amax = max(amax, __shfl_xor(amax, off));
    if (ln == 0) wmax[wv] = amax;
    __syncthreads();
    if (t == 0) {
        int m = wmax[0];
#pragma unroll
        for (int i = 1; i < 8; ++i) m = max(m, wmax[i]);
        atomicMax(maxAcc, (unsigned)m);
    }
}

// ---------------- requantize int32 accum -> f32 output, in place ----------------
__global__ __launch_bounds__(256) void k_requant(int4* __restrict__ buf, int n4,
                                                 const unsigned* __restrict__ sc) {
    const float maxX = __uint_as_float(sc[0]);
    const float maxW = __uint_as_float(sc[1]);
    const float maxA = (float)(int)sc[2];
    const float in_scale = 127.0f / maxX;
    const float w_scale  = 127.0f / maxW;
    const float accum_scale = in_scale * w_scale;
    const float requant = 127.0f / maxA;
    const float out_scale = requant * accum_scale;
    int stride = gridDim.x * blockDim.x;
    for (int i = blockIdx.x * blockDim.x + threadIdx.x; i < n4; i += stride) {
        int4 v = buf[i];
        float4 o;
        o.x = fminf(127.f, fmaxf(-128.f, rintf((float)v.x * requant))) / out_scale;
        o.y = fminf(127.f, fmaxf(-128.f, rintf((float)v.y * requant))) / out_scale;
        o.z = fminf(127.f, fmaxf(-128.f, rintf((float)v.z * requant))) / out_scale;
        o.w = fminf(127.f, fmaxf(-128.f, rintf((float)v.w * requant))) / out_scale;
        ((float4*)buf)[i] = o;
    }
}

extern "C" void kernel_launch(void* const* d_in, const int* in_sizes, int n_in,
                              void* d_out, int out_size, void* d_ws, size_t ws_size,
                              hipStream_t stream) {
    const float* x = (const float*)d_in[0];  // [8192, 4096]
    const float* W = (const float*)d_in[1];  // [4096, 4096]

    unsigned* sc = (unsigned*)d_ws;
    char* xq = (char*)d_ws + 256;
    char* wq = xq + (size_t)M_DIM * K_DIM;

    k_init<<<1, 1, 0, stream>>>(sc);
    k_absmax<<<2048, 256, 0, stream>>>((const float4*)x, M_DIM * K_DIM / 4, sc + 0);
    k_absmax<<<1024, 256, 0, stream>>>((const float4*)W, N_DIM * K_DIM / 4, sc + 1);
    k_quant<<<2048, 256, 0, stream>>>((const float4*)x, (unsigned*)xq, M_DIM * K_DIM / 4, sc + 0);
    k_quant<<<1024, 256, 0, stream>>>((const float4*)W, (unsigned*)wq, N_DIM * K_DIM / 4, sc + 1);

    k_gemm<<<(M_DIM / BM) * (N_DIM / BN), 512, 0, stream>>>(xq, wq, (int*)d_out, sc + 2);

    k_requant<<<2048, 256, 0, stream>>>((int4*)d_out, M_DIM * N_DIM / 4, sc);
}

// Round 3
// 297.397 us; speedup vs baseline: 1.1159x; 1.0375x over previous
//
#include <hip/hip_runtime.h>
#include <stdint.h>

// Quantized linear (distiller RangeLinearQuantParamLayerWrapper):
//   maxabs(x), maxabs(W) -> int8 quantize -> exact i8 GEMM (int32 accum)
//   -> maxabs(accum) -> requantize -> dequantize f32.
//
// GEMM: 256x256 tile, BK=128 i8, 8 waves, 8-phase counted-vmcnt schedule.
// This revision: precomputed ds_read offsets (immediate folding), precomputed
// 32-bit stage voffsets, kh-outer MFMA ordering, tail vmcnt drain fix.

using i32x4 = __attribute__((ext_vector_type(4))) int;

#define M_DIM 8192
#define N_DIM 4096
#define K_DIM 4096

#define BM 256
#define BN 256
#define BKB 128              // K-tile bytes (= i8 elements)
#define NKT (K_DIM / BKB)    // 32

// ---------------- scalar init ----------------
__global__ void k_init(unsigned* sc) {
    sc[0] = 0u;  // maxabs(x) bits
    sc[1] = 0u;  // maxabs(W) bits
    sc[2] = 0u;  // max|accum|
}

// ---------------- fused absmax over x and W ----------------
// blocks [0,2048) -> x (8M float4), [2048,3072) -> W (4M float4)
__global__ __launch_bounds__(256) void k_absmax2(const float4* __restrict__ x,
                                                 const float4* __restrict__ w,
                                                 unsigned* __restrict__ sc) {
    const bool isX = blockIdx.x < 2048;
    const float4* src = isX ? x : w;
    const int n4 = isX ? (M_DIM * K_DIM / 4) : (N_DIM * K_DIM / 4);
    const int brel = isX ? blockIdx.x : (blockIdx.x - 2048);
    const int nb = isX ? 2048 : 1024;
    unsigned m = 0;
    for (int i = brel * 256 + threadIdx.x; i < n4; i += nb * 256) {
        float4 v = src[i];
        unsigned a = __float_as_uint(v.x) & 0x7fffffffu;
        unsigned b = __float_as_uint(v.y) & 0x7fffffffu;
        unsigned c = __float_as_uint(v.z) & 0x7fffffffu;
        unsigned d = __float_as_uint(v.w) & 0x7fffffffu;
        m = max(m, max(max(a, b), max(c, d)));
    }
    for (int off = 32; off; off >>= 1)
        m = max(m, (unsigned)__shfl_xor((int)m, off));
    __shared__ unsigned wm[4];
    int ln = threadIdx.x & 63, wv = threadIdx.x >> 6;
    if (ln == 0) wm[wv] = m;
    __syncthreads();
    if (threadIdx.x == 0)
        atomicMax(sc + (isX ? 0 : 1), max(max(wm[0], wm[1]), max(wm[2], wm[3])));
}

// ---------------- fused symmetric int8 quantize of x and W ----------------
__global__ __launch_bounds__(256) void k_quant2(const float4* __restrict__ x,
                                                const float4* __restrict__ w,
                                                unsigned* __restrict__ xq,
                                                unsigned* __restrict__ wq,
                                                const unsigned* __restrict__ sc) {
    const bool isX = blockIdx.x < 2048;
    const float4* src = isX ? x : w;
    unsigned* dst = isX ? xq : wq;
    const int n4 = isX ? (M_DIM * K_DIM / 4) : (N_DIM * K_DIM / 4);
    const int brel = isX ? blockIdx.x : (blockIdx.x - 2048);
    const int nb = isX ? 2048 : 1024;
    const float scale = 127.0f / __uint_as_float(sc[isX ? 0 : 1]);
    for (int i = brel * 256 + threadIdx.x; i < n4; i += nb * 256) {
        float4 v = src[i];
        int q0 = min(127, max(-128, (int)rintf(v.x * scale)));
        int q1 = min(127, max(-128, (int)rintf(v.y * scale)));
        int q2 = min(127, max(-128, (int)rintf(v.z * scale)));
        int q3 = min(127, max(-128, (int)rintf(v.w * scale)));
        dst[i] = (unsigned)(q0 & 0xff) | ((unsigned)(q1 & 0xff) << 8) |
                 ((unsigned)(q2 & 0xff) << 16) | ((unsigned)(q3 & 0xff) << 24);
    }
}

// ---------------- i8 GEMM, 256^2 8-phase ----------------
// LDS: lA[2][256][128] @0, lB[2][256][128] @65536. XOR chunk swizzle:
// LDS slot cs holds global chunk cs^(row&7); linear gload_lds dest +
// inverse-swizzled global source + swizzled ds_read (both-sides rule).
// Key identity: frag rows r are (mult of 16)+lr so r&7 == lr&7 for ALL
// frags -> per-lane cs is frag-independent; cs(kh=1)=cs(kh=0)^4 -> all
// ds_read addrs = one VGPR base (+^64 variant) + compile-time offset.
__global__ __launch_bounds__(512, 2) void k_gemm(const char* __restrict__ Aq,
                                                 const char* __restrict__ Bq,
                                                 int* __restrict__ C,
                                                 unsigned* __restrict__ maxAcc) {
    __shared__ __align__(16) char lds[131072];
    __shared__ int wmax[8];

    const int t = threadIdx.x;
    const int ln = t & 63;
    const int wv = t >> 6;
    const int wr = wv >> 2;    // wave M half (0..1): rows wr*128..+127
    const int wc = wv & 3;     // wave N quarter (0..3): cols wc*64..+63
    const int lr = ln & 15;
    const int lk = ln >> 4;

    // XCD-aware swizzle: 512 wgs, 512%8==0 -> bijective
    const int bid = blockIdx.x;
    const int swz = (bid & 7) * 64 + (bid >> 3);
    const int bx = swz & 15;   // N tile (16)
    const int by = swz >> 4;   // M tile (32)
    const int arow0 = by * BM;
    const int brow0 = bx * BN;

    // ---- precomputed ds_read lane offsets ----
    const int cs0 = lk ^ (lr & 7);
    const int aoff0 = (((wr << 7) + lr) << 7) + (cs0 << 4);
    const int aoff1 = aoff0 ^ 64;                 // kh=1 (cs^4)
    const int boff0 = (((wc << 6) + lr) << 7) + (cs0 << 4);
    const int boff1 = boff0 ^ 64;

    // ---- precomputed stage lane voffsets (32-bit) ----
    int voffA[2], voffB[2];
#pragma unroll
    for (int it = 0; it < 2; ++it) {
        const int chunk = it * 512 + (wv << 6) + ln;
        const int row = chunk >> 3;                   // 0..127 within half
        const int gc = (chunk & 7) ^ (row & 7);       // inverse swizzle on src
        voffA[it] = (arow0 + row) * 4096 + (gc << 4);
        voffB[it] = (brow0 + row) * 4096 + (gc << 4);
    }

    i32x4 acc[8][4];
#pragma unroll
    for (int i = 0; i < 8; ++i)
#pragma unroll
        for (int j = 0; j < 4; ++j) acc[i][j] = (i32x4)(0);

    auto STAGE = [&](int kt, int j) {  // j: 0,1 = A halves; 2,3 = B halves
        const int slot = kt & 1;
        const int koff = kt * 128 + (j & 1) * 524288;  // (j&1)*128rows*4096
        const bool isA = (j < 2);
        const char* gbase = isA ? Aq : Bq;
        const int* voff = isA ? voffA : voffB;
        char* lbase = lds + (isA ? 0 : 65536) + (slot << 15) + ((j & 1) << 14) + (wv << 10);
#pragma unroll
        for (int it = 0; it < 2; ++it) {
            const char* g = gbase + (unsigned)(voff[it] + koff);
            __builtin_amdgcn_global_load_lds(
                (const __attribute__((address_space(1))) void*)g,
                (__attribute__((address_space(3))) void*)(lbase + (it << 13)), 16, 0, 0);
        }
    };

    // ---- prologue: stage kt0 + kt1 (16 loads), wait kt0 landed ----
#pragma unroll
    for (int h = 0; h < 8; ++h) STAGE(h >> 2, h & 3);
    asm volatile("s_waitcnt vmcnt(8)" ::: "memory");
    __builtin_amdgcn_s_barrier();
    __builtin_amdgcn_sched_barrier(0);

    for (int kt = 0; kt < NKT; ++kt) {
        const int sl = (kt & 1) << 15;
        const char* pA0 = lds + sl + aoff0;
        const char* pA1 = lds + sl + aoff1;
        const char* pB0 = lds + 65536 + sl + boff0;
        const char* pB1 = lds + 65536 + sl + boff1;
        i32x4 a0[4][2], a4[4][2], b0[2][2], b2[2][2];

        // ================ P0: read a03 + b01; MFMA a03 x b01 ================
#pragma unroll
        for (int mi = 0; mi < 4; ++mi) {
            a0[mi][0] = *(const i32x4*)(pA0 + (mi << 11));
            a0[mi][1] = *(const i32x4*)(pA1 + (mi << 11));
        }
#pragma unroll
        for (int ni = 0; ni < 2; ++ni) {
            b0[ni][0] = *(const i32x4*)(pB0 + (ni << 11));
            b0[ni][1] = *(const i32x4*)(pB1 + (ni << 11));
        }
        __builtin_amdgcn_s_barrier();
        __builtin_amdgcn_sched_barrier(0);
        asm volatile("s_waitcnt lgkmcnt(0)" ::: "memory");
        __builtin_amdgcn_sched_barrier(0);
        __builtin_amdgcn_s_setprio(1);
#pragma unroll
        for (int kh = 0; kh < 2; ++kh)
#pragma unroll
            for (int mi = 0; mi < 4; ++mi)
#pragma unroll
                for (int ni = 0; ni < 2; ++ni)
                    acc[mi][ni] = __builtin_amdgcn_mfma_i32_16x16x64_i8(
                        a0[mi][kh], b0[ni][kh], acc[mi][ni], 0, 0, 0);
        __builtin_amdgcn_s_setprio(0);
        __builtin_amdgcn_s_barrier();
        __builtin_amdgcn_sched_barrier(0);

        // ================ P1: read b23; MFMA a03 x b23 ================
#pragma unroll
        for (int ni = 0; ni < 2; ++ni) {
            b2[ni][0] = *(const i32x4*)(pB0 + ((ni + 2) << 11));
            b2[ni][1] = *(const i32x4*)(pB1 + ((ni + 2) << 11));
        }
        __builtin_amdgcn_s_barrier();
        __builtin_amdgcn_sched_barrier(0);
        asm volatile("s_waitcnt lgkmcnt(0)" ::: "memory");
        __builtin_amdgcn_sched_barrier(0);
        __builtin_amdgcn_s_setprio(1);
#pragma unroll
        for (int kh = 0; kh < 2; ++kh)
#pragma unroll
            for (int mi = 0; mi < 4; ++mi)
#pragma unroll
                for (int ni = 0; ni < 2; ++ni)
                    acc[mi][ni + 2] = __builtin_amdgcn_mfma_i32_16x16x64_i8(
                        a0[mi][kh], b2[ni][kh], acc[mi][ni + 2], 0, 0, 0);
        __builtin_amdgcn_s_setprio(0);
        __builtin_amdgcn_s_barrier();
        __builtin_amdgcn_sched_barrier(0);

        // ============ P2: read a47; stage B(kt+2); MFMA a47 x b01 ============
#pragma unroll
        for (int mi = 0; mi < 4; ++mi) {
            a4[mi][0] = *(const i32x4*)(pA0 + ((mi + 4) << 11));
            a4[mi][1] = *(const i32x4*)(pA1 + ((mi + 4) << 11));
        }
        if (kt + 2 < NKT) { STAGE(kt + 2, 2); STAGE(kt + 2, 3); }
        __builtin_amdgcn_s_barrier();
        __builtin_amdgcn_sched_barrier(0);
        asm volatile("s_waitcnt lgkmcnt(0)" ::: "memory");
        __builtin_amdgcn_sched_barrier(0);
        __builtin_amdgcn_s_setprio(1);
#pragma unroll
        for (int kh = 0; kh < 2; ++kh)
#pragma unroll
            for (int mi = 0; mi < 4; ++mi)
#pragma unroll
                for (int ni = 0; ni < 2; ++ni)
                    acc[mi + 4][ni] = __builtin_amdgcn_mfma_i32_16x16x64_i8(
                        a4[mi][kh], b0[ni][kh], acc[mi + 4][ni], 0, 0, 0);
        __builtin_amdgcn_s_setprio(0);
        __builtin_amdgcn_s_barrier();
        __builtin_amdgcn_sched_barrier(0);

        // ============ P3: stage A(kt+2); vmcnt; MFMA a47 x b23 ============
        if (kt + 2 < NKT) {
            STAGE(kt + 2, 0); STAGE(kt + 2, 1);
            asm volatile("s_waitcnt vmcnt(8)" ::: "memory");  // kt+1 landed, kt+2 in flight
        } else {
            asm volatile("s_waitcnt vmcnt(0)" ::: "memory");  // tail: force drain
        }
        __builtin_amdgcn_s_barrier();
        __builtin_amdgcn_sched_barrier(0);
        __builtin_amdgcn_s_setprio(1);
#pragma unroll
        for (int kh = 0; kh < 2; ++kh)
#pragma unroll
            for (int mi = 0; mi < 4; ++mi)
#pragma unroll
                for (int ni = 0; ni < 2; ++ni)
                    acc[mi + 4][ni + 2] = __builtin_amdgcn_mfma_i32_16x16x64_i8(
                        a4[mi][kh], b2[ni][kh], acc[mi + 4][ni + 2], 0, 0, 0);
        __builtin_amdgcn_s_setprio(0);
        __builtin_amdgcn_s_barrier();
        __builtin_amdgcn_sched_barrier(0);
    }

    // ---- epilogue: C write + |acc| max. C/D: col=lane&15, row=(lane>>4)*4+reg
    int amax = 0;
#pragma unroll
    for (int mi = 0; mi < 8; ++mi) {
#pragma unroll
        for (int ni = 0; ni < 4; ++ni) {
            const int row0 = arow0 + (wr << 7) + (mi << 4) + (lk << 2);
            const int col  = brow0 + (wc << 6) + (ni << 4) + lr;
            i32x4 v = acc[mi][ni];
#pragma unroll
            for (int j = 0; j < 4; ++j) {
                C[(size_t)(row0 + j) * N_DIM + col] = v[j];
                int a = v[j] < 0 ? -v[j] : v[j];
                amax = max(amax, a);
            }
        }
    }
    for (int off = 32; off; off >>= 1)
        amax = max(amax, __shfl_xor(amax, off));
    if (ln == 0) wmax[wv] = amax;
    __syncthreads();
    if (t == 0) {
        int m = wmax[0];
#pragma unroll
        for (int i = 1; i < 8; ++i) m = max(m, wmax[i]);
        atomicMax(maxAcc, (unsigned)m);
    }
}

// ---------------- requantize int32 accum -> f32 output, in place ----------------
__global__ __launch_bounds__(256) void k_requant(int4* __restrict__ buf, int n4,
                                                 const unsigned* __restrict__ sc) {
    const float maxX = __uint_as_float(sc[0]);
    const float maxW = __uint_as_float(sc[1]);
    const float maxA = (float)(int)sc[2];
    const float in_scale = 127.0f / maxX;
    const float w_scale  = 127.0f / maxW;
    const float accum_scale = in_scale * w_scale;
    const float requant = 127.0f / maxA;
    const float out_scale = requant * accum_scale;
    int stride = gridDim.x * blockDim.x;
    for (int i = blockIdx.x * blockDim.x + threadIdx.x; i < n4; i += stride) {
        int4 v = buf[i];
        float4 o;
        o.x = fminf(127.f, fmaxf(-128.f, rintf((float)v.x * requant))) / out_scale;
        o.y = fminf(127.f, fmaxf(-128.f, rintf((float)v.y * requant))) / out_scale;
        o.z = fminf(127.f, fmaxf(-128.f, rintf((float)v.z * requant))) / out_scale;
        o.w = fminf(127.f, fmaxf(-128.f, rintf((float)v.w * requant))) / out_scale;
        ((float4*)buf)[i] = o;
    }
}

extern "C" void kernel_launch(void* const* d_in, const int* in_sizes, int n_in,
                              void* d_out, int out_size, void* d_ws, size_t ws_size,
                              hipStream_t stream) {
    const float* x = (const float*)d_in[0];  // [8192, 4096]
    const float* W = (const float*)d_in[1];  // [4096, 4096]

    unsigned* sc = (unsigned*)d_ws;
    char* xq = (char*)d_ws + 256;
    char* wq = xq + (size_t)M_DIM * K_DIM;

    k_init<<<1, 1, 0, stream>>>(sc);
    k_absmax2<<<3072, 256, 0, stream>>>((const float4*)x, (const float4*)W, sc);
    k_quant2<<<3072, 256, 0, stream>>>((const float4*)x, (const float4*)W,
                                       (unsigned*)xq, (unsigned*)wq, sc);
    k_gemm<<<(M_DIM / BM) * (N_DIM / BN), 512, 0, stream>>>(xq, wq, (int*)d_out, sc + 2);
    k_requant<<<2048, 256, 0, stream>>>((int4*)d_out, M_DIM * N_DIM / 4, sc);
}

// Round 4
// 275.911 us; speedup vs baseline: 1.2028x; 1.0779x over previous
//
#include <hip/hip_runtime.h>
#include <stdint.h>

// Quantized linear (distiller RangeLinearQuantParamLayerWrapper):
//   maxabs(x), maxabs(W) -> int8 quantize -> exact i8 GEMM (int32 accum)
//   -> maxabs(accum) -> requantize -> dequantize f32.
//
// GEMM: 256x256 tile, BK=128 i8, 8 waves, 2-phase/K-tile counted-vmcnt
// schedule (32-MFMA clusters, ONE barrier per phase). Restage safety:
// a region is restaged only after a barrier that all waves reach with
// their reads of that region lgkm-drained:
//   A(kt+1) @ P0-start (prev P1 read a47(kt-1), drained before its barrier)
//   B(kt+2) @ P1-start (P0 read all b(kt), drained before P0's barrier)
// vmcnt(4) at P1: outstanding = B(kt+1),A(kt+1),B(kt+2) = 12 -> drain
// oldest 8 = tile kt+1 fully landed; B(kt+2) stays in flight.

using i32x4 = __attribute__((ext_vector_type(4))) int;

#define M_DIM 8192
#define N_DIM 4096
#define K_DIM 4096

#define BM 256
#define BN 256
#define BKB 128              // K-tile bytes (= i8 elements)
#define NKT (K_DIM / BKB)    // 32

// ---------------- scalar init ----------------
__global__ void k_init(unsigned* sc) {
    sc[0] = 0u;  // maxabs(x) bits
    sc[1] = 0u;  // maxabs(W) bits
    sc[2] = 0u;  // max|accum|
}

// ---------------- fused absmax over x and W ----------------
__global__ __launch_bounds__(256) void k_absmax2(const float4* __restrict__ x,
                                                 const float4* __restrict__ w,
                                                 unsigned* __restrict__ sc) {
    const bool isX = blockIdx.x < 2048;
    const float4* src = isX ? x : w;
    const int n4 = isX ? (M_DIM * K_DIM / 4) : (N_DIM * K_DIM / 4);
    const int brel = isX ? blockIdx.x : (blockIdx.x - 2048);
    const int nb = isX ? 2048 : 1024;
    unsigned m = 0;
    for (int i = brel * 256 + threadIdx.x; i < n4; i += nb * 256) {
        float4 v = src[i];
        unsigned a = __float_as_uint(v.x) & 0x7fffffffu;
        unsigned b = __float_as_uint(v.y) & 0x7fffffffu;
        unsigned c = __float_as_uint(v.z) & 0x7fffffffu;
        unsigned d = __float_as_uint(v.w) & 0x7fffffffu;
        m = max(m, max(max(a, b), max(c, d)));
    }
    for (int off = 32; off; off >>= 1)
        m = max(m, (unsigned)__shfl_xor((int)m, off));
    __shared__ unsigned wm[4];
    int ln = threadIdx.x & 63, wv = threadIdx.x >> 6;
    if (ln == 0) wm[wv] = m;
    __syncthreads();
    if (threadIdx.x == 0)
        atomicMax(sc + (isX ? 0 : 1), max(max(wm[0], wm[1]), max(wm[2], wm[3])));
}

// ---------------- fused symmetric int8 quantize of x and W ----------------
__global__ __launch_bounds__(256) void k_quant2(const float4* __restrict__ x,
                                                const float4* __restrict__ w,
                                                unsigned* __restrict__ xq,
                                                unsigned* __restrict__ wq,
                                                const unsigned* __restrict__ sc) {
    const bool isX = blockIdx.x < 2048;
    const float4* src = isX ? x : w;
    unsigned* dst = isX ? xq : wq;
    const int n4 = isX ? (M_DIM * K_DIM / 4) : (N_DIM * K_DIM / 4);
    const int brel = isX ? blockIdx.x : (blockIdx.x - 2048);
    const int nb = isX ? 2048 : 1024;
    const float scale = 127.0f / __uint_as_float(sc[isX ? 0 : 1]);
    for (int i = brel * 256 + threadIdx.x; i < n4; i += nb * 256) {
        float4 v = src[i];
        int q0 = min(127, max(-128, (int)rintf(v.x * scale)));
        int q1 = min(127, max(-128, (int)rintf(v.y * scale)));
        int q2 = min(127, max(-128, (int)rintf(v.z * scale)));
        int q3 = min(127, max(-128, (int)rintf(v.w * scale)));
        dst[i] = (unsigned)(q0 & 0xff) | ((unsigned)(q1 & 0xff) << 8) |
                 ((unsigned)(q2 & 0xff) << 16) | ((unsigned)(q3 & 0xff) << 24);
    }
}

// ---------------- i8 GEMM, 256^2, 2-phase/K-tile ----------------
__global__ __launch_bounds__(512, 2) void k_gemm(const char* __restrict__ Aq,
                                                 const char* __restrict__ Bq,
                                                 int* __restrict__ C,
                                                 unsigned* __restrict__ maxAcc) {
    __shared__ __align__(16) char lds[131072];
    __shared__ int wmax[8];

    const int t = threadIdx.x;
    const int ln = t & 63;
    const int wv = t >> 6;
    const int wr = wv >> 2;    // wave M half (0..1): rows wr*128..+127
    const int wc = wv & 3;     // wave N quarter (0..3): cols wc*64..+63
    const int lr = ln & 15;
    const int lk = ln >> 4;

    // XCD-aware swizzle: 512 wgs, 512%8==0 -> bijective
    const int bid = blockIdx.x;
    const int swz = (bid & 7) * 64 + (bid >> 3);
    const int bx = swz & 15;   // N tile (16)
    const int by = swz >> 4;   // M tile (32)
    const int arow0 = by * BM;
    const int brow0 = bx * BN;

    // ds_read lane offsets: rows r = 16*frag + lr, so r&7 == lr&7 for all
    // frags -> swizzled chunk slot cs is frag-independent; kh=1 slot = cs^4.
    const int cs0 = lk ^ (lr & 7);
    const int aoff0 = (((wr << 7) + lr) << 7) + (cs0 << 4);
    const int aoff1 = aoff0 ^ 64;
    const int boff0 = (((wc << 6) + lr) << 7) + (cs0 << 4);
    const int boff1 = boff0 ^ 64;

    // stage lane voffsets (32-bit)
    int voffA[2], voffB[2];
#pragma unroll
    for (int it = 0; it < 2; ++it) {
        const int chunk = it * 512 + (wv << 6) + ln;
        const int row = chunk >> 3;                   // 0..127 within half
        const int gc = (chunk & 7) ^ (row & 7);       // inverse swizzle on src
        voffA[it] = (arow0 + row) * 4096 + (gc << 4);
        voffB[it] = (brow0 + row) * 4096 + (gc << 4);
    }

    i32x4 acc[8][4];
#pragma unroll
    for (int i = 0; i < 8; ++i)
#pragma unroll
        for (int j = 0; j < 4; ++j) acc[i][j] = (i32x4)(0);

    auto STAGE = [&](int kt, int j) {  // j: 0,1 = A halves; 2,3 = B halves
        const int slot = kt & 1;
        const int koff = kt * 128 + (j & 1) * 524288;  // (j&1)*128rows*4096
        const bool isA = (j < 2);
        const char* gbase = isA ? Aq : Bq;
        const int* voff = isA ? voffA : voffB;
        char* lbase = lds + (isA ? 0 : 65536) + (slot << 15) + ((j & 1) << 14) + (wv << 10);
#pragma unroll
        for (int it = 0; it < 2; ++it) {
            const char* g = gbase + (unsigned)(voff[it] + koff);
            __builtin_amdgcn_global_load_lds(
                (const __attribute__((address_space(1))) void*)g,
                (__attribute__((address_space(3))) void*)(lbase + (it << 13)), 16, 0, 0);
        }
    };

    // ---- prologue: A(0), B(0), B(1); wait A0+B0 landed (B1 in flight) ----
    STAGE(0, 0); STAGE(0, 1); STAGE(0, 2); STAGE(0, 3);
    STAGE(1, 2); STAGE(1, 3);
    asm volatile("s_waitcnt vmcnt(4)" ::: "memory");
    __builtin_amdgcn_s_barrier();
    __builtin_amdgcn_sched_barrier(0);

    for (int kt = 0; kt < NKT; ++kt) {
        const int sl = (kt & 1) << 15;
        const char* pA0 = lds + sl + aoff0;
        const char* pA1 = lds + sl + aoff1;
        const char* pB0 = lds + 65536 + sl + boff0;
        const char* pB1 = lds + 65536 + sl + boff1;
        i32x4 a[4][2], b[4][2];

        // ========== P0: read a03 + b0123; stage A(kt+1); MFMA a03 x b ==========
#pragma unroll
        for (int mi = 0; mi < 4; ++mi) {
            a[mi][0] = *(const i32x4*)(pA0 + (mi << 11));
            a[mi][1] = *(const i32x4*)(pA1 + (mi << 11));
        }
#pragma unroll
        for (int ni = 0; ni < 4; ++ni) {
            b[ni][0] = *(const i32x4*)(pB0 + (ni << 11));
            b[ni][1] = *(const i32x4*)(pB1 + (ni << 11));
        }
        if (kt + 1 < NKT) { STAGE(kt + 1, 0); STAGE(kt + 1, 1); }
        __builtin_amdgcn_sched_barrier(0);
        asm volatile("s_waitcnt lgkmcnt(0)" ::: "memory");
        __builtin_amdgcn_sched_barrier(0);
        __builtin_amdgcn_s_setprio(1);
#pragma unroll
        for (int kh = 0; kh < 2; ++kh)
#pragma unroll
            for (int mi = 0; mi < 4; ++mi)
#pragma unroll
                for (int ni = 0; ni < 4; ++ni)
                    acc[mi][ni] = __builtin_amdgcn_mfma_i32_16x16x64_i8(
                        a[mi][kh], b[ni][kh], acc[mi][ni], 0, 0, 0);
        __builtin_amdgcn_s_setprio(0);
        __builtin_amdgcn_s_barrier();
        __builtin_amdgcn_sched_barrier(0);

        // ========== P1: read a47; stage B(kt+2); vmcnt; MFMA a47 x b ==========
#pragma unroll
        for (int mi = 0; mi < 4; ++mi) {
            a[mi][0] = *(const i32x4*)(pA0 + ((mi + 4) << 11));
            a[mi][1] = *(const i32x4*)(pA1 + ((mi + 4) << 11));
        }
        if (kt + 2 < NKT) {
            STAGE(kt + 2, 2); STAGE(kt + 2, 3);
            __builtin_amdgcn_sched_barrier(0);
            asm volatile("s_waitcnt vmcnt(4)" ::: "memory");  // tile kt+1 landed
        } else {
            __builtin_amdgcn_sched_barrier(0);
            asm volatile("s_waitcnt vmcnt(0)" ::: "memory");  // tail drain
        }
        __builtin_amdgcn_sched_barrier(0);
        asm volatile("s_waitcnt lgkmcnt(0)" ::: "memory");
        __builtin_amdgcn_sched_barrier(0);
        __builtin_amdgcn_s_setprio(1);
#pragma unroll
        for (int kh = 0; kh < 2; ++kh)
#pragma unroll
            for (int mi = 0; mi < 4; ++mi)
#pragma unroll
                for (int ni = 0; ni < 4; ++ni)
                    acc[mi + 4][ni] = __builtin_amdgcn_mfma_i32_16x16x64_i8(
                        a[mi][kh], b[ni][kh], acc[mi + 4][ni], 0, 0, 0);
        __builtin_amdgcn_s_setprio(0);
        __builtin_amdgcn_s_barrier();
        __builtin_amdgcn_sched_barrier(0);
    }

    // ---- epilogue: C write + |acc| max. C/D: col=lane&15, row=(lane>>4)*4+reg
    int amax = 0;
#pragma unroll
    for (int mi = 0; mi < 8; ++mi) {
#pragma unroll
        for (int ni = 0; ni < 4; ++ni) {
            const int row0 = arow0 + (wr << 7) + (mi << 4) + (lk << 2);
            const int col  = brow0 + (wc << 6) + (ni << 4) + lr;
            i32x4 v = acc[mi][ni];
#pragma unroll
            for (int j = 0; j < 4; ++j) {
                C[(size_t)(row0 + j) * N_DIM + col] = v[j];
                int a = v[j] < 0 ? -v[j] : v[j];
                amax = max(amax, a);
            }
        }
    }
    for (int off = 32; off; off >>= 1)
        amax = max(amax, __shfl_xor(amax, off));
    if (ln == 0) wmax[wv] = amax;
    __syncthreads();
    if (t == 0) {
        int m = wmax[0];
#pragma unroll
        for (int i = 1; i < 8; ++i) m = max(m, wmax[i]);
        atomicMax(maxAcc, (unsigned)m);
    }
}

// ---------------- requantize int32 accum -> f32 output, in place ----------------
__global__ __launch_bounds__(256) void k_requant(int4* __restrict__ buf, int n4,
                                                 const unsigned* __restrict__ sc) {
    const float maxX = __uint_as_float(sc[0]);
    const float maxW = __uint_as_float(sc[1]);
    const float maxA = (float)(int)sc[2];
    const float in_scale = 127.0f / maxX;
    const float w_scale  = 127.0f / maxW;
    const float accum_scale = in_scale * w_scale;
    const float requant = 127.0f / maxA;
    const float out_scale = requant * accum_scale;
    int stride = gridDim.x * blockDim.x;
    for (int i = blockIdx.x * blockDim.x + threadIdx.x; i < n4; i += stride) {
        int4 v = buf[i];
        float4 o;
        o.x = fminf(127.f, fmaxf(-128.f, rintf((float)v.x * requant))) / out_scale;
        o.y = fminf(127.f, fmaxf(-128.f, rintf((float)v.y * requant))) / out_scale;
        o.z = fminf(127.f, fmaxf(-128.f, rintf((float)v.z * requant))) / out_scale;
        o.w = fminf(127.f, fmaxf(-128.f, rintf((float)v.w * requant))) / out_scale;
        ((float4*)buf)[i] = o;
    }
}

extern "C" void kernel_launch(void* const* d_in, const int* in_sizes, int n_in,
                              void* d_out, int out_size, void* d_ws, size_t ws_size,
                              hipStream_t stream) {
    const float* x = (const float*)d_in[0];  // [8192, 4096]
    const float* W = (const float*)d_in[1];  // [4096, 4096]

    unsigned* sc = (unsigned*)d_ws;
    char* xq = (char*)d_ws + 256;
    char* wq = xq + (size_t)M_DIM * K_DIM;

    k_init<<<1, 1, 0, stream>>>(sc);
    k_absmax2<<<3072, 256, 0, stream>>>((const float4*)x, (const float4*)W, sc);
    k_quant2<<<3072, 256, 0, stream>>>((const float4*)x, (const float4*)W,
                                       (unsigned*)xq, (unsigned*)wq, sc);
    k_gemm<<<(M_DIM / BM) * (N_DIM / BN), 512, 0, stream>>>(xq, wq, (int*)d_out, sc + 2);
    k_requant<<<2048, 256, 0, stream>>>((int4*)d_out, M_DIM * N_DIM / 4, sc);
}